// Round 3
// baseline (850.522 us; speedup 1.0000x reference)
//
#include <hip/hip_runtime.h>

#define EPS 1e-15f

// ---------------- degree accumulation: one thread per edge ----------------
__global__ void k_deg(const int* __restrict__ ei, int E, float* __restrict__ deg) {
    int e = blockIdx.x * blockDim.x + threadIdx.x;
    if (e < E) atomicAdd(&deg[ei[E + e]], 1.0f);
}

// ------------- clamp degree, compute inv-sqrt-degree per node -------------
__global__ void k_isd(float* __restrict__ deg, float* __restrict__ isd, int n) {
    int i = blockIdx.x * blockDim.x + threadIdx.x;
    if (i < n) {
        float d = deg[i];
        d = d < 1.0f ? 1.0f : d;
        deg[i] = d;           // store clamped degree for mean-divide later
        isd[i] = rsqrtf(d);
    }
}

// ---------------- xt = x @ g  ([N,64] @ [64,256] -> [N,256]) ----------------
// g staged fully in LDS (64 KB). One wave per row; lane owns 4 consecutive
// output columns -> ds_read_b128 at lane*16B (conflict-free), float4 stores.
__global__ __launch_bounds__(256) void k_xt(const float* __restrict__ x,
                                            const float* __restrict__ g,
                                            float* __restrict__ xt, int n) {
    __shared__ float gs[64 * 256];
    for (int i = threadIdx.x; i < 64 * 256 / 4; i += 256)
        reinterpret_cast<float4*>(gs)[i] = reinterpret_cast<const float4*>(g)[i];
    __syncthreads();
    const int lane = threadIdx.x & 63;
    const int gw   = (blockIdx.x * blockDim.x + threadIdx.x) >> 6;
    const int nw   = (gridDim.x * blockDim.x) >> 6;
    for (int row = gw; row < n; row += nw) {
        float xv = x[row * 64 + lane];
        float a0 = 0.f, a1 = 0.f, a2 = 0.f, a3 = 0.f;
        #pragma unroll
        for (int dd = 0; dd < 64; ++dd) {
            float xb = __shfl(xv, dd);
            float4 gv = *reinterpret_cast<const float4*>(&gs[dd * 256 + 4 * lane]);
            a0 += xb * gv.x;
            a1 += xb * gv.y;
            a2 += xb * gv.z;
            a3 += xb * gv.w;
        }
        float4 o = {a0, a1, a2, a3};
        *reinterpret_cast<float4*>(&xt[(size_t)row * 256 + 4 * lane]) = o;
    }
}

// ------------------------- edge gather + scatter -------------------------
// One wave per edge (grid-stride). Lane = feature d. All 64 lanes load the
// same edge indices (HW broadcast). Gather xt[src,k,:] coalesced (256B per k),
// weighted-sum over K=4, one coalesced 256B atomic-add burst into agg[dst].
__global__ __launch_bounds__(256) void k_edge(const int* __restrict__ ei,
                                              const float* __restrict__ isd,
                                              const float* __restrict__ xt,
                                              const float* __restrict__ mu,
                                              const float* __restrict__ sigma,
                                              float* __restrict__ agg, int E) {
    const int lane = threadIdx.x & 63;
    const int wid  = (blockIdx.x * blockDim.x + threadIdx.x) >> 6;
    const int nw   = (gridDim.x * blockDim.x) >> 6;

    float mu0[4], mu1[4], w0[4], w1[4];
    #pragma unroll
    for (int k = 0; k < 4; ++k) {
        mu0[k] = mu[k * 2];
        mu1[k] = mu[k * 2 + 1];
        float s0 = sigma[k * 2], s1 = sigma[k * 2 + 1];
        w0[k] = -0.5f / (EPS + s0 * s0);
        w1[k] = -0.5f / (EPS + s1 * s1);
    }

    for (int e = wid; e < E; e += nw) {
        int src = ei[e];
        int dst = ei[E + e];
        float ps = isd[src];
        float pd = isd[dst];
        float gwv[4];
        #pragma unroll
        for (int k = 0; k < 4; ++k) {
            float d0 = ps - mu0[k], d1 = pd - mu1[k];
            gwv[k] = expf(d0 * d0 * w0[k] + d1 * d1 * w1[k]);
        }
        const float* xr = xt + (size_t)src * 256;
        float m = gwv[0] * xr[lane] + gwv[1] * xr[64 + lane] +
                  gwv[2] * xr[128 + lane] + gwv[3] * xr[192 + lane];
        atomicAdd(&agg[dst * 64 + lane], m);
    }
}

// --------- epilogue: out = x + relu(agg/deg + x@root + bias) ---------
// root (16 KB) in LDS; one wave per row, lane = output column.
__global__ __launch_bounds__(256) void k_out(const float* __restrict__ x,
                                             const float* __restrict__ root,
                                             const float* __restrict__ bias,
                                             const float* __restrict__ agg,
                                             const float* __restrict__ deg,
                                             float* __restrict__ out, int n) {
    __shared__ float rs[64 * 64];
    __shared__ float bs[64];
    for (int i = threadIdx.x; i < 64 * 64 / 4; i += 256)
        reinterpret_cast<float4*>(rs)[i] = reinterpret_cast<const float4*>(root)[i];
    if (threadIdx.x < 16)
        reinterpret_cast<float4*>(bs)[threadIdx.x] =
            reinterpret_cast<const float4*>(bias)[threadIdx.x];
    __syncthreads();
    const int lane = threadIdx.x & 63;
    const int gw   = (blockIdx.x * blockDim.x + threadIdx.x) >> 6;
    const int nw   = (gridDim.x * blockDim.x) >> 6;
    for (int row = gw; row < n; row += nw) {
        float xv  = x[row * 64 + lane];
        float acc = bs[lane];
        #pragma unroll
        for (int dd = 0; dd < 64; ++dd)
            acc += __shfl(xv, dd) * rs[dd * 64 + lane];
        float a    = agg[row * 64 + lane] / deg[row];
        float conv = a + acc;
        out[row * 64 + lane] = xv + (conv > 0.f ? conv : 0.f);
    }
}

extern "C" void kernel_launch(void* const* d_in, const int* in_sizes, int n_in,
                              void* d_out, int out_size, void* d_ws, size_t ws_size,
                              hipStream_t stream) {
    const float* x     = (const float*)d_in[0];
    const int*   ei    = (const int*)d_in[1];
    const float* g     = (const float*)d_in[2];
    const float* mu    = (const float*)d_in[3];
    const float* sigma = (const float*)d_in[4];
    const float* root  = (const float*)d_in[5];
    const float* bias  = (const float*)d_in[6];
    float* out = (float*)d_out;

    const int n = in_sizes[0] / 64;   // 100000
    const int E = in_sizes[1] / 2;    // 1600000

    // workspace layout (floats):
    //   deg [0, n) | isd [102400, +n) | xt [204800, +n*256) | agg (+n*64)
    float* ws  = (float*)d_ws;
    float* deg = ws;
    float* isd = ws + 102400;
    float* xt  = ws + 204800;
    float* agg = xt + (size_t)n * 256;
    // total: (204800 + n*256 + n*64)*4 ≈ 128.9 MB

    hipMemsetAsync(deg, 0, (size_t)n * sizeof(float), stream);
    hipMemsetAsync(agg, 0, (size_t)n * 64 * sizeof(float), stream);

    k_deg<<<(E + 255) / 256, 256, 0, stream>>>(ei, E, deg);
    k_isd<<<(n + 255) / 256, 256, 0, stream>>>(deg, isd, n);
    k_xt<<<512, 256, 0, stream>>>(x, g, xt, n);
    k_edge<<<8192, 256, 0, stream>>>(ei, isd, xt, mu, sigma, agg, E);
    k_out<<<1024, 256, 0, stream>>>(x, root, bias, agg, deg, out, n);
}